// Round 3
// baseline (168.723 us; speedup 1.0000x reference)
//
#include <hip/hip_runtime.h>

#define NJ 8
#define TS 2048
#define NB 1024
#define RSTEPS 8
#define CHUNK 512              // 64 lanes * 8 steps per wave-scan
#define NCH (TS / CHUNK)       // 4
#define F4_PER_CHUNK (CHUNK * NJ)   // 4096 float4 = 64 KB
#define DTC (1.0f / 60.0f)

__global__ __launch_bounds__(512, 4) void phys_scan8_kernel(
    const float4* __restrict__ x,       // (B,T,8) as float4 per (t,joint)
    const float*  __restrict__ state0,  // (B,8,2)
    const float*  __restrict__ M,       // (8,2)
    const float*  __restrict__ inertia, // (8,)
    const float*  __restrict__ damping, // (8,)
    float* __restrict__ out,            // (B,T,8)
    float* __restrict__ muscle,         // (B,8,2,2)
    float* __restrict__ finals)         // (B,8,2)
{
    __shared__ float4 lds[F4_PER_CHUNK];   // 64 KB, single-buffered

    const int b    = blockIdx.x;
    const int tid  = threadIdx.x;
    const int j    = tid >> 6;          // wave id = joint index
    const int lane = tid & 63;

    const float M0  = M[j * 2 + 0];
    const float M1  = M[j * 2 + 1];
    const float M20 = M0 * M0;
    const float M21 = M1 * M1;
    const float d   = damping[j];
    const float p   = DTC / inertia[j];      // DT / I
    const float g   = 1.0f - p * d;          // dθ self-coefficient

    float thc  = state0[(b * NJ + j) * 2 + 0];
    float dthc = state0[(b * NJ + j) * 2 + 1];

    const float4* xb = x + (size_t)b * TS * NJ;

    // prologue: prefetch chunk 0 (coalesced: lane-adjacent float4)
    float4 stage[8];
    #pragma unroll
    for (int i = 0; i < 8; ++i) stage[i] = xb[512 * i + tid];

    for (int ch = 0; ch < NCH; ++ch) {
        // stage -> LDS, XOR-swizzled: idx' = idx ^ ((idx>>6)&7)  (conflict-free)
        #pragma unroll
        for (int i = 0; i < 8; ++i) {
            int idx = 512 * i + tid;
            lds[idx ^ ((idx >> 6) & 7)] = stage[i];
        }
        __syncthreads();

        // prefetch next chunk (latency hides under scan compute)
        if (ch + 1 < NCH) {
            #pragma unroll
            for (int i = 0; i < 8; ++i)
                stage[i] = xb[(size_t)(ch + 1) * F4_PER_CHUNK + 512 * i + tid];
        }

        // read my 8 consecutive steps (steps lane*8+k), compute a,c per step
        // element (step s, joint j) lives at swizzled idx 64*l + 8*k + (j^(l&7))
        float a[8], c[8];
        const int base = 64 * lane + (j ^ (lane & 7));
        #pragma unroll
        for (int k = 0; k < 8; ++k) {
            float4 v = lds[base + 8 * k];
            a[k] = fmaf(M0,  v.x, M1  * v.y);   // einsum(M, F_t)
            c[k] = fmaf(M20, v.z, M21 * v.w);   // einsum(M2, K_t)
        }

        // serially compose my 8 step-maps:
        //   dθ' = r0·θ + r1·dθ + rc ;  θ' = s0·θ + s1·dθ + sc
        float r0 = 0.0f, r1 = 1.0f, rc = 0.0f;   // identity
        float s0 = 1.0f, s1 = 0.0f, sc = 0.0f;
        #pragma unroll
        for (int k = 0; k < 8; ++k) {
            float pa = p * a[k];
            float pc = p * c[k];
            float nr0 = fmaf(-pc, s0, g * r0);
            float nr1 = fmaf(-pc, s1, g * r1);
            float nrc = fmaf(-pc, sc, fmaf(g, rc, pa));
            s0 = fmaf(DTC, nr0, s0);
            s1 = fmaf(DTC, nr1, s1);
            sc = fmaf(DTC, nrc, sc);
            r0 = nr0; r1 = nr1; rc = nrc;
        }

        // inclusive Kogge-Stone over 64 lanes (compose: mine ∘ other)
        #pragma unroll
        for (int delta = 1; delta < 64; delta <<= 1) {
            float o_r0 = __shfl_up(r0, delta, 64);
            float o_r1 = __shfl_up(r1, delta, 64);
            float o_rc = __shfl_up(rc, delta, 64);
            float o_s0 = __shfl_up(s0, delta, 64);
            float o_s1 = __shfl_up(s1, delta, 64);
            float o_sc = __shfl_up(sc, delta, 64);
            if (lane >= delta) {
                float nr0 = fmaf(r0, o_s0, r1 * o_r0);
                float nr1 = fmaf(r0, o_s1, r1 * o_r1);
                float nrc = fmaf(r0, o_sc, fmaf(r1, o_rc, rc));
                float ns0 = fmaf(s0, o_s0, s1 * o_r0);
                float ns1 = fmaf(s0, o_s1, s1 * o_r1);
                float nsc = fmaf(s0, o_sc, fmaf(s1, o_rc, sc));
                r0 = nr0; r1 = nr1; rc = nrc;
                s0 = ns0; s1 = ns1; sc = nsc;
            }
        }

        // exclusive prefix: lane l uses inclusive result of lane l-1
        float e_r0 = __shfl_up(r0, 1, 64);
        float e_r1 = __shfl_up(r1, 1, 64);
        float e_rc = __shfl_up(rc, 1, 64);
        float e_s0 = __shfl_up(s0, 1, 64);
        float e_s1 = __shfl_up(s1, 1, 64);
        float e_sc = __shfl_up(sc, 1, 64);
        if (lane == 0) {
            e_r0 = 0.0f; e_r1 = 1.0f; e_rc = 0.0f;
            e_s0 = 1.0f; e_s1 = 0.0f; e_sc = 0.0f;
        }

        // state at my first step
        float th  = fmaf(e_s0, thc, fmaf(e_s1, dthc, e_sc));
        float dth = fmaf(e_r0, thc, fmaf(e_r1, dthc, e_rc));

        // replay 8 steps in exact reference op-order, emit θ per step
        float* outp = out + ((size_t)(b * TS + ch * CHUNK + lane * 8)) * NJ + j;
        #pragma unroll
        for (int k = 0; k < 8; ++k) {
            float u = fmaf(-c[k], th, a[k]);     // a - c·θ
            u = fmaf(-d, dth, u);                // ... - d·dθ
            dth = fmaf(p, u, dth);
            th  = fmaf(DTC, dth, th);
            outp[k * NJ] = th;
        }

        // carry = lane 63's end state
        thc  = __shfl(th, 63, 64);
        dthc = __shfl(dth, 63, 64);

        __syncthreads();   // all reads done before buffer is overwritten
    }

    if (lane == 0) {
        const int idx = b * NJ + j;
        finals[idx * 2 + 0] = thc;
        finals[idx * 2 + 1] = dthc;
        muscle[idx * 4 + 0] = thc  * M0;
        muscle[idx * 4 + 1] = thc  * M1;
        muscle[idx * 4 + 2] = dthc * M0;
        muscle[idx * 4 + 3] = dthc * M1;
    }
}

extern "C" void kernel_launch(void* const* d_in, const int* in_sizes, int n_in,
                              void* d_out, int out_size, void* d_ws, size_t ws_size,
                              hipStream_t stream) {
    const float4* x      = (const float4*)d_in[0];
    const float*  state0 = (const float*)d_in[1];
    const float*  M      = (const float*)d_in[2];
    const float*  inertia= (const float*)d_in[3];
    const float*  damping= (const float*)d_in[4];

    float* out    = (float*)d_out;                       // (B,T,8)
    float* muscle = out + (size_t)NB * TS * NJ;          // (B,8,2,2)
    float* finals = muscle + (size_t)NB * NJ * 2 * 2;    // (B,8,2)

    dim3 block(512);          // 8 waves = 8 joints of one batch
    dim3 grid(NB);
    phys_scan8_kernel<<<grid, block, 0, stream>>>(x, state0, M, inertia, damping,
                                                  out, muscle, finals);
}

// Round 4
// 131.154 us; speedup vs baseline: 1.2864x; 1.2864x over previous
//
#include <hip/hip_runtime.h>

#define NJ 8
#define TS 2048
#define NB 1024
#define CHUNK 512              // 64 lanes * 8 steps per wave-scan
#define NCH (TS / CHUNK)       // 4
#define F4C (CHUNK * NJ)       // 4096 float4 = 64 KB
#define DTC (1.0f / 60.0f)

__global__ __launch_bounds__(512, 4) void phys_scan8t_kernel(
    const float4* __restrict__ x,       // (B,T,8) as float4 per (t,joint)
    const float*  __restrict__ state0,  // (B,8,2)
    const float*  __restrict__ M,       // (8,2)
    const float*  __restrict__ inertia, // (8,)
    const float*  __restrict__ damping, // (8,)
    float* __restrict__ out,            // (B,T,8)
    float* __restrict__ muscle,         // (B,8,2,2)
    float* __restrict__ finals)         // (B,8,2)
{
    __shared__ float4 xin[F4C];            // 64 KB input chunk
    __shared__ float4 tout4[CHUNK * NJ/4]; // 16 KB theta transpose buffer
    float* tout = (float*)tout4;

    const int b    = blockIdx.x;
    const int tid  = threadIdx.x;
    const int j    = tid >> 6;          // wave id = joint index
    const int lane = tid & 63;

    const float M0  = M[j * 2 + 0];
    const float M1  = M[j * 2 + 1];
    const float M20 = M0 * M0;
    const float M21 = M1 * M1;
    const float d   = damping[j];
    const float p   = DTC / inertia[j];      // DT / I
    const float g   = 1.0f - p * d;          // dθ self-coefficient

    float thc  = state0[(b * NJ + j) * 2 + 0];
    float dthc = state0[(b * NJ + j) * 2 + 1];

    const float4* xb = x + (size_t)b * TS * NJ;

    // prologue: prefetch chunk 0 and stage it
    float4 stage[8];
    #pragma unroll
    for (int i = 0; i < 8; ++i) stage[i] = xb[512 * i + tid];
    #pragma unroll
    for (int i = 0; i < 8; ++i) {
        int idx = 512 * i + tid;
        xin[idx ^ ((idx >> 6) & 7)] = stage[i];
    }

    for (int ch = 0; ch < NCH; ++ch) {
        __syncthreads();   // S1: staging visible; prev θ-reads complete

        // prefetch next chunk into regs (drains after S2, overlapped w/ compute)
        if (ch + 1 < NCH) {
            #pragma unroll
            for (int i = 0; i < 8; ++i)
                stage[i] = xb[(size_t)(ch + 1) * F4C + 512 * i + tid];
        }

        // read my 8 consecutive steps; element (step s=8*lane+k, joint j)
        // lives at swizzled idx 64*lane + 8*k + (j ^ (lane&7))
        float a[8], c[8];
        const int base = 64 * lane + (j ^ (lane & 7));
        #pragma unroll
        for (int k = 0; k < 8; ++k) {
            float4 v = xin[base + 8 * k];
            a[k] = fmaf(M0,  v.x, M1  * v.y);   // einsum(M, F_t)
            c[k] = fmaf(M20, v.z, M21 * v.w);   // einsum(M2, K_t)
        }

        // serially compose my 8 step-maps:
        //   dθ' = r0·θ + r1·dθ + rc ;  θ' = s0·θ + s1·dθ + sc
        float r0 = 0.0f, r1 = 1.0f, rc = 0.0f;   // identity
        float s0 = 1.0f, s1 = 0.0f, sc = 0.0f;
        #pragma unroll
        for (int k = 0; k < 8; ++k) {
            float pa = p * a[k];
            float pc = p * c[k];
            float nr0 = fmaf(-pc, s0, g * r0);
            float nr1 = fmaf(-pc, s1, g * r1);
            float nrc = fmaf(-pc, sc, fmaf(g, rc, pa));
            s0 = fmaf(DTC, nr0, s0);
            s1 = fmaf(DTC, nr1, s1);
            sc = fmaf(DTC, nrc, sc);
            r0 = nr0; r1 = nr1; rc = nrc;
        }

        // inclusive Kogge-Stone over 64 lanes (compose: mine ∘ other)
        #pragma unroll
        for (int delta = 1; delta < 64; delta <<= 1) {
            float o_r0 = __shfl_up(r0, delta, 64);
            float o_r1 = __shfl_up(r1, delta, 64);
            float o_rc = __shfl_up(rc, delta, 64);
            float o_s0 = __shfl_up(s0, delta, 64);
            float o_s1 = __shfl_up(s1, delta, 64);
            float o_sc = __shfl_up(sc, delta, 64);
            if (lane >= delta) {
                float nr0 = fmaf(r0, o_s0, r1 * o_r0);
                float nr1 = fmaf(r0, o_s1, r1 * o_r1);
                float nrc = fmaf(r0, o_sc, fmaf(r1, o_rc, rc));
                float ns0 = fmaf(s0, o_s0, s1 * o_r0);
                float ns1 = fmaf(s0, o_s1, s1 * o_r1);
                float nsc = fmaf(s0, o_sc, fmaf(s1, o_rc, sc));
                r0 = nr0; r1 = nr1; rc = nrc;
                s0 = ns0; s1 = ns1; sc = nsc;
            }
        }

        // exclusive prefix: lane l uses inclusive result of lane l-1
        float e_r0 = __shfl_up(r0, 1, 64);
        float e_r1 = __shfl_up(r1, 1, 64);
        float e_rc = __shfl_up(rc, 1, 64);
        float e_s0 = __shfl_up(s0, 1, 64);
        float e_s1 = __shfl_up(s1, 1, 64);
        float e_sc = __shfl_up(sc, 1, 64);
        if (lane == 0) {
            e_r0 = 0.0f; e_r1 = 1.0f; e_rc = 0.0f;
            e_s0 = 1.0f; e_s1 = 0.0f; e_sc = 0.0f;
        }

        // state at my first step
        float th  = fmaf(e_s0, thc, fmaf(e_s1, dthc, e_sc));
        float dth = fmaf(e_r0, thc, fmaf(e_r1, dthc, e_rc));

        // replay 8 steps in exact reference op-order; θ -> LDS transpose buf.
        // natural word W = (8*lane+k)*8 + j = 64*lane + 8k + j
        // swizzled  W' = W ^ ((W>>6)&31) = W ^ (lane&31)  -> 2 lanes/bank
        #pragma unroll
        for (int k = 0; k < 8; ++k) {
            float u = fmaf(-c[k], th, a[k]);     // a - c·θ
            u = fmaf(-d, dth, u);                // ... - d·dθ
            dth = fmaf(p, u, dth);
            th  = fmaf(DTC, dth, th);
            tout[(64 * lane + 8 * k + j) ^ (lane & 31)] = th;
        }

        // carry = lane 63's end state
        thc  = __shfl(th, 63, 64);
        dthc = __shfl(dth, 63, 64);

        __syncthreads();   // S2: θ visible; all a,c reads complete

        // stage next chunk into input LDS (safe: a,c reads done at S2)
        if (ch + 1 < NCH) {
            #pragma unroll
            for (int i = 0; i < 8; ++i) {
                int idx = 512 * i + tid;
                xin[idx ^ ((idx >> 6) & 7)] = stage[i];
            }
        }

        // coalesced output: thread handles float4 f = tid, tid+512.
        // out word o = 8t + jb + i (i=0..3); stored in tout at o^m, m=(t>>3)&31.
        // b128 read at aligned block X^(m&~3), components permuted by i^(m&3).
        float* outc = out + ((size_t)b * TS + (size_t)ch * CHUNK) * NJ;
        #pragma unroll
        for (int h = 0; h < 2; ++h) {
            int f  = tid + 512 * h;
            int t  = f >> 1;
            int X  = 8 * t + 4 * (f & 1);
            int m  = (t >> 3) & 31;
            int pm = m & 3;
            float4 r = tout4[(X ^ (m & ~3)) >> 2];
            float rx = r.x, ry = r.y, rz = r.z, rw = r.w;
            if (pm & 1) { float tq = rx; rx = ry; ry = tq; tq = rz; rz = rw; rw = tq; }
            if (pm & 2) { float tq = rx; rx = rz; rz = tq; tq = ry; ry = rw; rw = tq; }
            ((float4*)outc)[f] = make_float4(rx, ry, rz, rw);
        }
    }

    if (lane == 0) {
        const int idx = b * NJ + j;
        finals[idx * 2 + 0] = thc;
        finals[idx * 2 + 1] = dthc;
        muscle[idx * 4 + 0] = thc  * M0;
        muscle[idx * 4 + 1] = thc  * M1;
        muscle[idx * 4 + 2] = dthc * M0;
        muscle[idx * 4 + 3] = dthc * M1;
    }
}

extern "C" void kernel_launch(void* const* d_in, const int* in_sizes, int n_in,
                              void* d_out, int out_size, void* d_ws, size_t ws_size,
                              hipStream_t stream) {
    const float4* x      = (const float4*)d_in[0];
    const float*  state0 = (const float*)d_in[1];
    const float*  M      = (const float*)d_in[2];
    const float*  inertia= (const float*)d_in[3];
    const float*  damping= (const float*)d_in[4];

    float* out    = (float*)d_out;                       // (B,T,8)
    float* muscle = out + (size_t)NB * TS * NJ;          // (B,8,2,2)
    float* finals = muscle + (size_t)NB * NJ * 2 * 2;    // (B,8,2)

    dim3 block(512);          // 8 waves = 8 joints of one batch
    dim3 grid(NB);
    phys_scan8t_kernel<<<grid, block, 0, stream>>>(x, state0, M, inertia, damping,
                                                   out, muscle, finals);
}